// Round 3
// baseline (281.276 us; speedup 1.0000x reference)
//
#include <hip/hip_runtime.h>
#include <hip/hip_bf16.h>

using bf16 = __hip_bfloat16;
typedef __attribute__((ext_vector_type(4))) float f32x4;
typedef short s16x8 __attribute__((ext_vector_type(8)));
typedef unsigned short u16x8 __attribute__((ext_vector_type(8)));

__device__ __forceinline__ unsigned short f2b(float f) {
  bf16 h = __float2bfloat16(f);
  return __builtin_bit_cast(unsigned short, h);
}
__device__ __forceinline__ float b2f(unsigned short u) {
  bf16 h = __builtin_bit_cast(bf16, u);
  return __bfloat162float(h);
}

__device__ __forceinline__ void async_copy16(const void* g, void* lds) {
  __builtin_amdgcn_global_load_lds(
      (const __attribute__((address_space(1))) void*)g,
      (__attribute__((address_space(3))) void*)lds, 16, 0, 0);
}

// ---------------- fp32 -> bf16 convert (8 elems/thread) ----------------
__global__ __launch_bounds__(256) void cvt_f32_to_bf16(const float* __restrict__ in,
                                                       ushort* __restrict__ out) {
  long i = ((long)blockIdx.x * 256 + threadIdx.x) * 8;
  float4 a = *(const float4*)(in + i);
  float4 b = *(const float4*)(in + i + 4);
  u16x8 o;
  o[0] = f2b(a.x); o[1] = f2b(a.y); o[2] = f2b(a.z); o[3] = f2b(a.w);
  o[4] = f2b(b.x); o[5] = f2b(b.y); o[6] = f2b(b.z); o[7] = f2b(b.w);
  *(u16x8*)(out + i) = o;
}

// ---------------- RoPE in-place on q,k halves; q additionally scaled ------
// q *= 0.125*log2(e) so attention softmax runs in exp2 domain with no muls.
__global__ __launch_bounds__(256) void rope_kernel(ushort* __restrict__ qkv,
                                                   const float* __restrict__ cosT,
                                                   const float* __restrict__ sinT) {
  long idx = (long)blockIdx.x * 256 + threadIdx.x;  // 2,097,152 total
  int d4 = (int)(idx & 7) * 4;
  int h = (int)((idx >> 3) & 15);
  int which = (int)((idx >> 7) & 1);
  long row = idx >> 8;          // 0..8191
  int s = (int)(row & 2047);
  long base = row * 3072 + which * 1024 + h * 64 + d4;
  float sc = which ? 1.0f : 0.18033688011112042f;  // q gets scale*log2e
  ushort4 lo = *(ushort4*)(qkv + base);
  ushort4 hi = *(ushort4*)(qkv + base + 32);
  float4 c0 = *(const float4*)(cosT + s * 64 + d4);
  float4 c1 = *(const float4*)(cosT + s * 64 + d4 + 32);
  float4 s0 = *(const float4*)(sinT + s * 64 + d4);
  float4 s1 = *(const float4*)(sinT + s * 64 + d4 + 32);
  float l0 = b2f(lo.x), l1 = b2f(lo.y), l2 = b2f(lo.z), l3 = b2f(lo.w);
  float h0 = b2f(hi.x), h1 = b2f(hi.y), h2 = b2f(hi.z), h3 = b2f(hi.w);
  ushort4 olo, ohi;
  olo.x = f2b((l0 * c0.x - h0 * s0.x) * sc); ohi.x = f2b((h0 * c1.x + l0 * s1.x) * sc);
  olo.y = f2b((l1 * c0.y - h1 * s0.y) * sc); ohi.y = f2b((h1 * c1.y + l1 * s1.y) * sc);
  olo.z = f2b((l2 * c0.z - h2 * s0.z) * sc); ohi.z = f2b((h2 * c1.z + l2 * s1.z) * sc);
  olo.w = f2b((l3 * c0.w - h3 * s0.w) * sc); ohi.w = f2b((h3 * c1.w + l3 * s1.w) * sc);
  *(ushort4*)(qkv + base) = olo;
  *(ushort4*)(qkv + base + 32) = ohi;
}

// ---------------- V transpose: qkv V-part -> vtg[pair][d][2048] ----------
__global__ __launch_bounds__(256) void transpose_v(const bf16* __restrict__ qkv,
                                                   ushort* __restrict__ vtg) {
  const int pair = blockIdx.y;
  const int b = pair >> 4, h = pair & 15;
  const int st = blockIdx.x * 64;
  const int tid = threadIdx.x;
  __shared__ ushort T[64][68];
  const ushort* src = (const ushort*)qkv + (long)(b * 2048 + st) * 3072 + 2048 + h * 64;
#pragma unroll
  for (int i = 0; i < 4; ++i) {
    int c2 = tid + i * 256;
    int row = c2 >> 4;          // s_local
    int d4 = (c2 & 15) * 4;
    *(ushort4*)&T[row][d4] = *(const ushort4*)(src + (long)row * 3072 + d4);
  }
  __syncthreads();
#pragma unroll
  for (int i = 0; i < 4; ++i) {
    int c2 = tid + i * 256;
    int d = c2 >> 4;
    int s4 = (c2 & 15) * 4;
    ushort4 w;
    w.x = T[s4][d]; w.y = T[s4 + 1][d]; w.z = T[s4 + 2][d]; w.w = T[s4 + 3][d];
    *(ushort4*)(vtg + (long)pair * 131072 + (long)d * 2048 + st + s4) = w;
  }
}

// ---------------- bf16 GEMM: C[M][N] = A[M][K] * B[N][K]^T ----------------
__device__ __forceinline__ void storeC(float* p, float v) { *p = v; }
__device__ __forceinline__ void storeC(bf16* p, float v) { *p = __float2bfloat16(v); }

template <typename CT>
__global__ __launch_bounds__(256) void gemm_bt(const bf16* __restrict__ A,
                                               const bf16* __restrict__ B,
                                               CT* __restrict__ C,
                                               int M, int N, int K) {
  __shared__ bf16 As[128 * 64];
  __shared__ bf16 Bs[128 * 64];
  const int tid = threadIdx.x;
  const int lane = tid & 63;
  const int wid = tid >> 6;
  const int tm = blockIdx.y * 128;
  const int tn = blockIdx.x * 128;
  const int wr = wid >> 1, wc = wid & 1;
  const int srow = tid >> 3;
  const int scol = (tid & 7) * 8;

  f32x4 acc[4][4] = {};

  const bf16* Abase = A + (long)(tm + srow) * K + scol;
  const bf16* Bbase = B + (long)(tn + srow) * K + scol;

  const int lr = lane & 15;
  const int lk = (lane >> 4) * 8;

  for (int k0 = 0; k0 < K; k0 += 64) {
#pragma unroll
    for (int i = 0; i < 4; ++i) {
      async_copy16(Abase + (long)i * 32 * K + k0, (char*)As + wid * 1024 + i * 4096);
      async_copy16(Bbase + (long)i * 32 * K + k0, (char*)Bs + wid * 1024 + i * 4096);
    }
    __syncthreads();
#pragma unroll
    for (int ks = 0; ks < 2; ++ks) {
      s16x8 af[4], bff[4];
#pragma unroll
      for (int m = 0; m < 4; ++m)
        af[m] = *(const s16x8*)&As[(wr * 64 + m * 16 + lr) * 64 + ks * 32 + lk];
#pragma unroll
      for (int n = 0; n < 4; ++n)
        bff[n] = *(const s16x8*)&Bs[(wc * 64 + n * 16 + lr) * 64 + ks * 32 + lk];
#pragma unroll
      for (int m = 0; m < 4; ++m)
#pragma unroll
        for (int n = 0; n < 4; ++n)
          acc[m][n] = __builtin_amdgcn_mfma_f32_16x16x32_bf16(af[m], bff[n], acc[m][n], 0, 0, 0);
    }
    __syncthreads();
  }

  const int cc = lane & 15;
  const int cr = (lane >> 4) * 4;
#pragma unroll
  for (int m = 0; m < 4; ++m)
#pragma unroll
    for (int n = 0; n < 4; ++n) {
      long row0 = tm + wr * 64 + m * 16 + cr;
      long col = tn + wc * 64 + n * 16 + cc;
#pragma unroll
      for (int r = 0; r < 4; ++r)
        storeC(&C[(row0 + r) * (long)N + col], acc[m][n][r]);
    }
}

// ---------------- flash attention, swapped QK^T, dbuf prefetch ----------
// grid: (16 q-tiles, 64 (b,h)), 256 threads = 4 waves, 32 q-rows/wave.
__global__ __launch_bounds__(256) void attn_kernel(const bf16* __restrict__ qkv,
                                                   const ushort* __restrict__ vtg,
                                                   ushort* __restrict__ o) {
  const int pair = blockIdx.y;
  const int b = pair >> 4, h = pair & 15;
  const int q0 = blockIdx.x * 128;
  const int tid = threadIdx.x, lane = tid & 63, wid = tid >> 6;

  const bf16* Qb = qkv + (long)b * 2048 * 3072 + h * 64;
  const bf16* Kb = Qb + 1024;
  const ushort* Vg = vtg + (long)pair * 131072;   // [64 d][2048 keys]

  __shared__ bf16 Ks[2][64 * 64];    // [key][d], rows 128B, XOR-swizzled
  __shared__ bf16 Vs[2][64 * 64];    // [d][key], rows 128B, XOR-swizzled
  __shared__ ushort Ps[4][32 * 64];  // per-wave [q][key], rows 128B, XOR-swizzled

  const int lr = lane & 15;
  const int g = lane >> 4;
  const int lk = g * 8;
  const int sw = (lr & 7) << 4;      // per-lane XOR (row&7 == lr&7 everywhere)

  // Q fragments (B operand of swapped QK^T); q pre-scaled by scale*log2e
  s16x8 qa[2][2];
#pragma unroll
  for (int m = 0; m < 2; ++m)
#pragma unroll
    for (int ks = 0; ks < 2; ++ks)
      qa[m][ks] = *(const s16x8*)(Qb + (long)(q0 + wid * 32 + m * 16 + lr) * 3072 + ks * 32 + lk);

  f32x4 oacc[2][4] = {};
  float mrow[2] = {-1e30f, -1e30f};
  float lrow[2] = {0.f, 0.f};

  // stage K tile [64 keys][64 d] + Vt tile [64 d][64 keys], swizzled source
  auto stage = [&](int kt, int bb) {
#pragma unroll
    for (int i = 0; i < 2; ++i) {
      int cidx = tid + i * 256;
      int row = cidx >> 3;
      int colb = (cidx & 7) * 16;
      int scolb = colb ^ ((row & 7) << 4);
      async_copy16(Kb + (long)(kt * 64 + row) * 3072 + (scolb >> 1),
                   (char*)Ks[bb] + wid * 1024 + i * 4096);
      async_copy16(Vg + (long)row * 2048 + kt * 64 + (scolb >> 1),
                   (char*)Vs[bb] + wid * 1024 + i * 4096);
    }
  };

  stage(0, 0);
  __syncthreads();

  for (int kt = 0; kt < 32; ++kt) {
    const int cur = kt & 1;
    if (kt < 31) stage(kt + 1, cur ^ 1);   // prefetch next tile into other buf

    // S^T = K Q^T : sacc[n][m], row = key_local(g*4+r), col = q_local(lr)
    f32x4 sacc[4][2] = {};
    __builtin_amdgcn_s_setprio(1);
#pragma unroll
    for (int ks = 0; ks < 2; ++ks) {
      s16x8 kf[4];
#pragma unroll
      for (int n = 0; n < 4; ++n) {
        int row = n * 16 + lr;
        kf[n] = *(const s16x8*)((const char*)Ks[cur] + row * 128 + ((ks * 64 + g * 16) ^ sw));
      }
#pragma unroll
      for (int n = 0; n < 4; ++n)
#pragma unroll
        for (int m = 0; m < 2; ++m)
          sacc[n][m] = __builtin_amdgcn_mfma_f32_16x16x32_bf16(kf[n], qa[m][ks], sacc[n][m], 0, 0, 0);
    }
    __builtin_amdgcn_s_setprio(0);

    // ---- softmax (exp2 domain; S already scaled via q) ----
    float vmax[2];
#pragma unroll
    for (int m = 0; m < 2; ++m) {
      float t = -1e30f;
#pragma unroll
      for (int n = 0; n < 4; ++n)
#pragma unroll
        for (int r = 0; r < 4; ++r)
          t = fmaxf(t, sacc[n][m][r]);
      t = fmaxf(t, __shfl_xor(t, 16, 64));
      t = fmaxf(t, __shfl_xor(t, 32, 64));
      vmax[m] = t;
    }
    bool need = !__all((vmax[0] <= mrow[0] + 8.f) && (vmax[1] <= mrow[1] + 8.f));
    if (need) {
#pragma unroll
      for (int m = 0; m < 2; ++m) {
        float mnew = fmaxf(mrow[m], vmax[m]);
        float al = exp2f(mrow[m] - mnew);
        mrow[m] = mnew;
        lrow[m] *= al;
#pragma unroll
        for (int r = 0; r < 4; ++r) {
          float a = __shfl(al, (g << 2) + r, 64);
#pragma unroll
          for (int n2 = 0; n2 < 4; ++n2) oacc[m][n2][r] *= a;
        }
      }
    }
#pragma unroll
    for (int m = 0; m < 2; ++m) {
      float ps = 0.f;
      char* pbase = (char*)&Ps[wid][0] + (m * 16 + lr) * 128;
#pragma unroll
      for (int n = 0; n < 4; ++n) {
        float p0 = exp2f(sacc[n][m][0] - mrow[m]);
        float p1 = exp2f(sacc[n][m][1] - mrow[m]);
        float p2 = exp2f(sacc[n][m][2] - mrow[m]);
        float p3 = exp2f(sacc[n][m][3] - mrow[m]);
        ps += (p0 + p1) + (p2 + p3);
        ushort4 w;
        w.x = f2b(p0); w.y = f2b(p1); w.z = f2b(p2); w.w = f2b(p3);
        *(ushort4*)(pbase + ((n * 32 + g * 8) ^ sw)) = w;
      }
      ps += __shfl_xor(ps, 16, 64);
      ps += __shfl_xor(ps, 32, 64);
      lrow[m] += ps;
    }

    // O += P V : A = P rows (q), B = Vs rows (d)
    __builtin_amdgcn_s_setprio(1);
#pragma unroll
    for (int ks = 0; ks < 2; ++ks) {
      s16x8 pa[2], vf[4];
#pragma unroll
      for (int m = 0; m < 2; ++m)
        pa[m] = *(const s16x8*)((const char*)&Ps[wid][0] + (m * 16 + lr) * 128 +
                                ((ks * 64 + g * 16) ^ sw));
#pragma unroll
      for (int n = 0; n < 4; ++n) {
        int row = n * 16 + lr;
        vf[n] = *(const s16x8*)((const char*)Vs[cur] + row * 128 + ((ks * 64 + g * 16) ^ sw));
      }
#pragma unroll
      for (int m = 0; m < 2; ++m)
#pragma unroll
        for (int n = 0; n < 4; ++n)
          oacc[m][n] = __builtin_amdgcn_mfma_f32_16x16x32_bf16(pa[m], vf[n], oacc[m][n], 0, 0, 0);
    }
    __builtin_amdgcn_s_setprio(0);

    __syncthreads();   // drains prefetch (had whole compute to land) + gates buf reuse
  }

  // epilogue: O/l -> o[b*2048+s][h*64+d] (bf16)
#pragma unroll
  for (int m = 0; m < 2; ++m)
#pragma unroll
    for (int r = 0; r < 4; ++r) {
      float inv = 1.f / __shfl(lrow[m], (g << 2) + r, 64);
      int rl = g * 4 + r;
      long srow = q0 + wid * 32 + m * 16 + rl;
#pragma unroll
      for (int n = 0; n < 4; ++n) {
        int d = n * 16 + lr;
        o[((long)b * 2048 + srow) * 1024 + h * 64 + d] = f2b(oacc[m][n][r] * inv);
      }
    }
}

// ---------------- launch ----------------
extern "C" void kernel_launch(void* const* d_in, const int* in_sizes, int n_in,
                              void* d_out, int out_size, void* d_ws, size_t ws_size,
                              hipStream_t stream) {
  const float* x    = (const float*)d_in[0];
  const float* cosT = (const float*)d_in[1];
  const float* sinT = (const float*)d_in[2];
  const float* Wqkv = (const float*)d_in[3];
  const float* Wout = (const float*)d_in[4];
  float* out = (float*)d_out;

  char* p = (char*)d_ws;
  bf16* xb    = (bf16*)p; p += (size_t)8192 * 1024 * 2;   // dead after gemm1; reused as vtg
  bf16* wqkvb = (bf16*)p; p += (size_t)3072 * 1024 * 2;
  bf16* woutb = (bf16*)p; p += (size_t)1024 * 1024 * 2;
  bf16* qkvb  = (bf16*)p; p += (size_t)8192 * 3072 * 2;
  bf16* ob    = (bf16*)p;
  ushort* vtg = (ushort*)xb;   // 64*64*2048 ushorts == xb's 16.8 MB exactly

  cvt_f32_to_bf16<<<4096, 256, 0, stream>>>(x, (ushort*)xb);
  cvt_f32_to_bf16<<<1536, 256, 0, stream>>>(Wqkv, (ushort*)wqkvb);
  cvt_f32_to_bf16<<<512, 256, 0, stream>>>(Wout, (ushort*)woutb);

  // qkv = x @ Wqkv^T : M=8192, N=3072, K=1024
  gemm_bt<bf16><<<dim3(24, 64), 256, 0, stream>>>(xb, wqkvb, qkvb, 8192, 3072, 1024);

  rope_kernel<<<8192, 256, 0, stream>>>((ushort*)qkvb, cosT, sinT);

  // vtg[pair][d][s] <- V (x/xb no longer needed)
  transpose_v<<<dim3(32, 64), 256, 0, stream>>>(qkvb, vtg);

  attn_kernel<<<dim3(16, 64), 256, 0, stream>>>(qkvb, vtg, (ushort*)ob);

  // out = o @ Wout^T : M=8192, N=1024, K=1024 (fp32 out)
  gemm_bt<float><<<dim3(8, 64), 256, 0, stream>>>(ob, woutb, out, 8192, 1024, 1024);
}

// Round 4
// 267.827 us; speedup vs baseline: 1.0502x; 1.0502x over previous
//
#include <hip/hip_runtime.h>
#include <hip/hip_bf16.h>

using bf16 = __hip_bfloat16;
typedef __attribute__((ext_vector_type(4))) float f32x4;
typedef short s16x8 __attribute__((ext_vector_type(8)));
typedef unsigned short u16x8 __attribute__((ext_vector_type(8)));

__device__ __forceinline__ unsigned short f2b(float f) {
  bf16 h = __float2bfloat16(f);
  return __builtin_bit_cast(unsigned short, h);
}
__device__ __forceinline__ float b2f(unsigned short u) {
  bf16 h = __builtin_bit_cast(bf16, u);
  return __bfloat162float(h);
}

__device__ __forceinline__ void async_copy16(const void* g, void* lds) {
  __builtin_amdgcn_global_load_lds(
      (const __attribute__((address_space(1))) void*)g,
      (__attribute__((address_space(3))) void*)lds, 16, 0, 0);
}

// ---------------- fp32 -> bf16 convert (8 elems/thread) ----------------
__global__ __launch_bounds__(256) void cvt_f32_to_bf16(const float* __restrict__ in,
                                                       ushort* __restrict__ out) {
  long i = ((long)blockIdx.x * 256 + threadIdx.x) * 8;
  float4 a = *(const float4*)(in + i);
  float4 b = *(const float4*)(in + i + 4);
  u16x8 o;
  o[0] = f2b(a.x); o[1] = f2b(a.y); o[2] = f2b(a.z); o[3] = f2b(a.w);
  o[4] = f2b(b.x); o[5] = f2b(b.y); o[6] = f2b(b.z); o[7] = f2b(b.w);
  *(u16x8*)(out + i) = o;
}

// ---------------- RoPE in-place on q,k halves; q additionally scaled ------
// q *= 0.125*log2(e) so attention softmax runs in exp2 domain with no muls.
__global__ __launch_bounds__(256) void rope_kernel(ushort* __restrict__ qkv,
                                                   const float* __restrict__ cosT,
                                                   const float* __restrict__ sinT) {
  long idx = (long)blockIdx.x * 256 + threadIdx.x;  // 2,097,152 total
  int d4 = (int)(idx & 7) * 4;
  int h = (int)((idx >> 3) & 15);
  int which = (int)((idx >> 7) & 1);
  long row = idx >> 8;          // 0..8191
  int s = (int)(row & 2047);
  long base = row * 3072 + which * 1024 + h * 64 + d4;
  float sc = which ? 1.0f : 0.18033688011112042f;  // q gets scale*log2e
  ushort4 lo = *(ushort4*)(qkv + base);
  ushort4 hi = *(ushort4*)(qkv + base + 32);
  float4 c0 = *(const float4*)(cosT + s * 64 + d4);
  float4 c1 = *(const float4*)(cosT + s * 64 + d4 + 32);
  float4 s0 = *(const float4*)(sinT + s * 64 + d4);
  float4 s1 = *(const float4*)(sinT + s * 64 + d4 + 32);
  float l0 = b2f(lo.x), l1 = b2f(lo.y), l2 = b2f(lo.z), l3 = b2f(lo.w);
  float h0 = b2f(hi.x), h1 = b2f(hi.y), h2 = b2f(hi.z), h3 = b2f(hi.w);
  ushort4 olo, ohi;
  olo.x = f2b((l0 * c0.x - h0 * s0.x) * sc); ohi.x = f2b((h0 * c1.x + l0 * s1.x) * sc);
  olo.y = f2b((l1 * c0.y - h1 * s0.y) * sc); ohi.y = f2b((h1 * c1.y + l1 * s1.y) * sc);
  olo.z = f2b((l2 * c0.z - h2 * s0.z) * sc); ohi.z = f2b((h2 * c1.z + l2 * s1.z) * sc);
  olo.w = f2b((l3 * c0.w - h3 * s0.w) * sc); ohi.w = f2b((h3 * c1.w + l3 * s1.w) * sc);
  *(ushort4*)(qkv + base) = olo;
  *(ushort4*)(qkv + base + 32) = ohi;
}

// ---------------- V transpose: qkv V-part -> vtg[pair][d][2048] ----------
__global__ __launch_bounds__(256) void transpose_v(const bf16* __restrict__ qkv,
                                                   ushort* __restrict__ vtg) {
  const int pair = blockIdx.y;
  const int b = pair >> 4, h = pair & 15;
  const int st = blockIdx.x * 64;
  const int tid = threadIdx.x;
  __shared__ ushort T[64][68];
  const ushort* src = (const ushort*)qkv + (long)(b * 2048 + st) * 3072 + 2048 + h * 64;
#pragma unroll
  for (int i = 0; i < 4; ++i) {
    int c2 = tid + i * 256;
    int row = c2 >> 4;          // s_local
    int d4 = (c2 & 15) * 4;
    *(ushort4*)&T[row][d4] = *(const ushort4*)(src + (long)row * 3072 + d4);
  }
  __syncthreads();
#pragma unroll
  for (int i = 0; i < 4; ++i) {
    int c2 = tid + i * 256;
    int d = c2 >> 4;
    int s4 = (c2 & 15) * 4;
    ushort4 w;
    w.x = T[s4][d]; w.y = T[s4 + 1][d]; w.z = T[s4 + 2][d]; w.w = T[s4 + 3][d];
    *(ushort4*)(vtg + (long)pair * 131072 + (long)d * 2048 + st + s4) = w;
  }
}

// ---------------- bf16 GEMM: C[M][N] = A[M][K] * B[N][K]^T ----------------
__device__ __forceinline__ void storeC(float* p, float v) { *p = v; }
__device__ __forceinline__ void storeC(bf16* p, float v) { *p = __float2bfloat16(v); }

template <typename CT>
__global__ __launch_bounds__(256) void gemm_bt(const bf16* __restrict__ A,
                                               const bf16* __restrict__ B,
                                               CT* __restrict__ C,
                                               int M, int N, int K) {
  __shared__ bf16 As[128 * 64];
  __shared__ bf16 Bs[128 * 64];
  const int tid = threadIdx.x;
  const int lane = tid & 63;
  const int wid = tid >> 6;
  const int tm = blockIdx.y * 128;
  const int tn = blockIdx.x * 128;
  const int wr = wid >> 1, wc = wid & 1;
  const int srow = tid >> 3;
  const int scol = (tid & 7) * 8;

  f32x4 acc[4][4] = {};

  const bf16* Abase = A + (long)(tm + srow) * K + scol;
  const bf16* Bbase = B + (long)(tn + srow) * K + scol;

  const int lr = lane & 15;
  const int lk = (lane >> 4) * 8;

  for (int k0 = 0; k0 < K; k0 += 64) {
#pragma unroll
    for (int i = 0; i < 4; ++i) {
      async_copy16(Abase + (long)i * 32 * K + k0, (char*)As + wid * 1024 + i * 4096);
      async_copy16(Bbase + (long)i * 32 * K + k0, (char*)Bs + wid * 1024 + i * 4096);
    }
    __syncthreads();
#pragma unroll
    for (int ks = 0; ks < 2; ++ks) {
      s16x8 af[4], bff[4];
#pragma unroll
      for (int m = 0; m < 4; ++m)
        af[m] = *(const s16x8*)&As[(wr * 64 + m * 16 + lr) * 64 + ks * 32 + lk];
#pragma unroll
      for (int n = 0; n < 4; ++n)
        bff[n] = *(const s16x8*)&Bs[(wc * 64 + n * 16 + lr) * 64 + ks * 32 + lk];
#pragma unroll
      for (int m = 0; m < 4; ++m)
#pragma unroll
        for (int n = 0; n < 4; ++n)
          acc[m][n] = __builtin_amdgcn_mfma_f32_16x16x32_bf16(af[m], bff[n], acc[m][n], 0, 0, 0);
    }
    __syncthreads();
  }

  const int cc = lane & 15;
  const int cr = (lane >> 4) * 4;
#pragma unroll
  for (int m = 0; m < 4; ++m)
#pragma unroll
    for (int n = 0; n < 4; ++n) {
      long row0 = tm + wr * 64 + m * 16 + cr;
      long col = tn + wc * 64 + n * 16 + cc;
#pragma unroll
      for (int r = 0; r < 4; ++r)
        storeC(&C[(row0 + r) * (long)N + col], acc[m][n][r]);
    }
}

// ---------------- flash attention, swapped QK^T, T14 reg-staged prefetch --
// grid: (16 q-tiles, 64 (b,h)), 256 threads = 4 waves, 32 q-rows/wave.
// LDS 32KB -> 4 blocks/CU resident (grid is exactly 4 blocks/CU).
__global__ __launch_bounds__(256, 4) void attn_kernel(const bf16* __restrict__ qkv,
                                                      const ushort* __restrict__ vtg,
                                                      ushort* __restrict__ o) {
  const int pair = blockIdx.y;
  const int b = pair >> 4, h = pair & 15;
  const int q0 = blockIdx.x * 128;
  const int tid = threadIdx.x, lane = tid & 63, wid = tid >> 6;

  const bf16* Qb = qkv + (long)b * 2048 * 3072 + h * 64;
  const bf16* Kb = Qb + 1024;
  const ushort* Vg = vtg + (long)pair * 131072;   // [64 d][2048 keys]

  __shared__ bf16 Ks[64 * 64];       // [key][d], 128B rows, XOR-swizzled
  __shared__ bf16 Vs[64 * 64];       // [d][key], 128B rows, XOR-swizzled
  __shared__ ushort Ps[4][32 * 64];  // per-wave [q][key], XOR-swizzled

  const int lr = lane & 15;
  const int g = lane >> 4;
  const int lk = g * 8;
  const int sw = (lr & 7) << 4;

  // staging geometry: thread owns 16B of rows srow and srow+32
  const int srow = tid >> 3;              // 0..31
  const int scolb = (tid & 7) * 16;       // byte col in 128B row
  const int kdst = srow * 128 + (scolb ^ ((srow & 7) << 4));  // (srow+32)&7==srow&7
  const ushort* Kg = (const ushort*)Kb + (long)srow * 3072 + (scolb >> 1);
  const ushort* Vgp = Vg + (long)srow * 2048 + (scolb >> 1);

  // Q fragments (B operand of swapped QK^T); q pre-scaled by scale*log2e
  s16x8 qa[2][2];
#pragma unroll
  for (int m = 0; m < 2; ++m)
#pragma unroll
    for (int ks = 0; ks < 2; ++ks)
      qa[m][ks] = *(const s16x8*)(Qb + (long)(q0 + wid * 32 + m * 16 + lr) * 3072 + ks * 32 + lk);

  f32x4 oacc[2][4] = {};
  float mrow[2] = {-1e30f, -1e30f};
  float lrow[2] = {0.f, 0.f};

  // prologue: stage tile 0 through registers
  {
    int4 k0 = *(const int4*)(Kg);
    int4 k1 = *(const int4*)(Kg + 32 * 3072);
    int4 v0 = *(const int4*)(Vgp);
    int4 v1 = *(const int4*)(Vgp + 32 * 2048);
    *(int4*)((char*)Ks + kdst) = k0;
    *(int4*)((char*)Ks + kdst + 4096) = k1;
    *(int4*)((char*)Vs + kdst) = v0;
    *(int4*)((char*)Vs + kdst + 4096) = v1;
  }
  __syncthreads();

  for (int kt = 0; kt < 32; ++kt) {
    // T14 issue-early: next tile -> regs (latency hides under this tile's compute)
    const long ktn = (kt < 31) ? kt + 1 : 31;
    int4 nk0 = *(const int4*)(Kg + ktn * 64 * 3072);
    int4 nk1 = *(const int4*)(Kg + ktn * 64 * 3072 + 32 * 3072);
    int4 nv0 = *(const int4*)(Vgp + ktn * 64);
    int4 nv1 = *(const int4*)(Vgp + ktn * 64 + 32 * 2048);

    // S^T = K Q^T : sacc[n][m], row = key_local(g*4+r), col = q_local(lr)
    f32x4 sacc[4][2] = {};
    __builtin_amdgcn_s_setprio(1);
#pragma unroll
    for (int ks = 0; ks < 2; ++ks) {
      s16x8 kf[4];
#pragma unroll
      for (int n = 0; n < 4; ++n) {
        int row = n * 16 + lr;
        kf[n] = *(const s16x8*)((const char*)Ks + row * 128 + ((ks * 64 + g * 16) ^ sw));
      }
#pragma unroll
      for (int n = 0; n < 4; ++n)
#pragma unroll
        for (int m = 0; m < 2; ++m)
          sacc[n][m] = __builtin_amdgcn_mfma_f32_16x16x32_bf16(kf[n], qa[m][ks], sacc[n][m], 0, 0, 0);
    }
    __builtin_amdgcn_s_setprio(0);

    // ---- softmax (exp2 domain; S already scaled via q) ----
    float vmax[2];
#pragma unroll
    for (int m = 0; m < 2; ++m) {
      float a0 = fmaxf(fmaxf(sacc[0][m][0], sacc[0][m][1]), fmaxf(sacc[0][m][2], sacc[0][m][3]));
      float a1 = fmaxf(fmaxf(sacc[1][m][0], sacc[1][m][1]), fmaxf(sacc[1][m][2], sacc[1][m][3]));
      float a2 = fmaxf(fmaxf(sacc[2][m][0], sacc[2][m][1]), fmaxf(sacc[2][m][2], sacc[2][m][3]));
      float a3 = fmaxf(fmaxf(sacc[3][m][0], sacc[3][m][1]), fmaxf(sacc[3][m][2], sacc[3][m][3]));
      float t = fmaxf(fmaxf(a0, a1), fmaxf(a2, a3));
      t = fmaxf(t, __shfl_xor(t, 16, 64));
      t = fmaxf(t, __shfl_xor(t, 32, 64));
      vmax[m] = t;
    }
    bool need = !__all((vmax[0] <= mrow[0] + 8.f) && (vmax[1] <= mrow[1] + 8.f));
    if (need) {
#pragma unroll
      for (int m = 0; m < 2; ++m) {
        float mnew = fmaxf(mrow[m], vmax[m]);
        float al = exp2f(mrow[m] - mnew);
        mrow[m] = mnew;
        lrow[m] *= al;
#pragma unroll
        for (int r = 0; r < 4; ++r) {
          float a = __shfl(al, (g << 2) + r, 64);
#pragma unroll
          for (int n2 = 0; n2 < 4; ++n2) oacc[m][n2][r] *= a;
        }
      }
    }
#pragma unroll
    for (int m = 0; m < 2; ++m) {
      float psn[4];
      char* pbase = (char*)&Ps[wid][0] + (m * 16 + lr) * 128;
#pragma unroll
      for (int n = 0; n < 4; ++n) {
        float p0 = exp2f(sacc[n][m][0] - mrow[m]);
        float p1 = exp2f(sacc[n][m][1] - mrow[m]);
        float p2 = exp2f(sacc[n][m][2] - mrow[m]);
        float p3 = exp2f(sacc[n][m][3] - mrow[m]);
        psn[n] = (p0 + p1) + (p2 + p3);
        ushort4 w;
        w.x = f2b(p0); w.y = f2b(p1); w.z = f2b(p2); w.w = f2b(p3);
        *(ushort4*)(pbase + ((n * 32 + g * 8) ^ sw)) = w;
      }
      float ps = (psn[0] + psn[1]) + (psn[2] + psn[3]);
      ps += __shfl_xor(ps, 16, 64);
      ps += __shfl_xor(ps, 32, 64);
      lrow[m] += ps;
    }

    // O += P V : A = P rows (q), B = Vs rows (d)
    __builtin_amdgcn_s_setprio(1);
#pragma unroll
    for (int ks = 0; ks < 2; ++ks) {
      s16x8 pa[2], vf[4];
#pragma unroll
      for (int m = 0; m < 2; ++m)
        pa[m] = *(const s16x8*)((const char*)&Ps[wid][0] + (m * 16 + lr) * 128 +
                                ((ks * 64 + g * 16) ^ sw));
#pragma unroll
      for (int n = 0; n < 4; ++n) {
        int row = n * 16 + lr;
        vf[n] = *(const s16x8*)((const char*)Vs + row * 128 + ((ks * 64 + g * 16) ^ sw));
      }
#pragma unroll
      for (int m = 0; m < 2; ++m)
#pragma unroll
        for (int n = 0; n < 4; ++n)
          oacc[m][n] = __builtin_amdgcn_mfma_f32_16x16x32_bf16(pa[m], vf[n], oacc[m][n], 0, 0, 0);
    }
    __builtin_amdgcn_s_setprio(0);

    __syncthreads();                   // all waves done reading Ks/Vs
    if (kt < 31) {
      *(int4*)((char*)Ks + kdst) = nk0;          // write-late: staged regs -> LDS
      *(int4*)((char*)Ks + kdst + 4096) = nk1;
      *(int4*)((char*)Vs + kdst) = nv0;
      *(int4*)((char*)Vs + kdst + 4096) = nv1;
      __syncthreads();                 // new tile visible
    }
  }

  // epilogue: O/l -> o[b*2048+s][h*64+d] (bf16)
#pragma unroll
  for (int m = 0; m < 2; ++m)
#pragma unroll
    for (int r = 0; r < 4; ++r) {
      float inv = 1.f / __shfl(lrow[m], (g << 2) + r, 64);
      int rl = g * 4 + r;
      long srow2 = q0 + wid * 32 + m * 16 + rl;
#pragma unroll
      for (int n = 0; n < 4; ++n) {
        int d = n * 16 + lr;
        o[((long)b * 2048 + srow2) * 1024 + h * 64 + d] = f2b(oacc[m][n][r] * inv);
      }
    }
}

// ---------------- launch ----------------
extern "C" void kernel_launch(void* const* d_in, const int* in_sizes, int n_in,
                              void* d_out, int out_size, void* d_ws, size_t ws_size,
                              hipStream_t stream) {
  const float* x    = (const float*)d_in[0];
  const float* cosT = (const float*)d_in[1];
  const float* sinT = (const float*)d_in[2];
  const float* Wqkv = (const float*)d_in[3];
  const float* Wout = (const float*)d_in[4];
  float* out = (float*)d_out;

  char* p = (char*)d_ws;
  bf16* xb    = (bf16*)p; p += (size_t)8192 * 1024 * 2;   // dead after gemm1; reused as vtg
  bf16* wqkvb = (bf16*)p; p += (size_t)3072 * 1024 * 2;
  bf16* woutb = (bf16*)p; p += (size_t)1024 * 1024 * 2;
  bf16* qkvb  = (bf16*)p; p += (size_t)8192 * 3072 * 2;
  bf16* ob    = (bf16*)p;
  ushort* vtg = (ushort*)xb;   // 64*64*2048 ushorts == xb's 16.8 MB exactly

  cvt_f32_to_bf16<<<4096, 256, 0, stream>>>(x, (ushort*)xb);
  cvt_f32_to_bf16<<<1536, 256, 0, stream>>>(Wqkv, (ushort*)wqkvb);
  cvt_f32_to_bf16<<<512, 256, 0, stream>>>(Wout, (ushort*)woutb);

  // qkv = x @ Wqkv^T : M=8192, N=3072, K=1024
  gemm_bt<bf16><<<dim3(24, 64), 256, 0, stream>>>(xb, wqkvb, qkvb, 8192, 3072, 1024);

  rope_kernel<<<8192, 256, 0, stream>>>((ushort*)qkvb, cosT, sinT);

  // vtg[pair][d][s] <- V (x/xb no longer needed)
  transpose_v<<<dim3(32, 64), 256, 0, stream>>>(qkvb, vtg);

  attn_kernel<<<dim3(16, 64), 256, 0, stream>>>(qkvb, vtg, (ushort*)ob);

  // out = o @ Wout^T : M=8192, N=1024, K=1024 (fp32 out)
  gemm_bt<float><<<dim3(8, 64), 256, 0, stream>>>(ob, woutb, out, 8192, 1024, 1024);
}